// Round 8
// baseline (162.972 us; speedup 1.0000x reference)
//
#include <hip/hip_runtime.h>
#include <math.h>

// CRF forward: B=64, C=2, T=65536.
// Log-semiring matrix scan: alpha_t = A_t (x) alpha_{t-1},
//   A_t[i][j] = trans[i][j] + emit_t[i]
// Parallel chunked scan with 2x2 transfer matrices, base-2 logs
// (LSE = 1x v_exp_f32 + 1x v_log_f32, both native HW).
// R8: fuse the final combine into the scan kernel (atomic-ticket last-block)
// to remove the 2nd dispatch + gap. Body identical to R7 (lean, straight-line
// loads, no arrays -> no spills; launch_bounds(256,1) grants full VGPR budget).

#define T_LEN   65536
#define NT      256       // threads per block (4 waves)
#define STEPS   8         // timesteps per thread
#define SEG     (NT * STEPS)      // 2048 per block
#define NSEG    32        // segments per batch
#define NBATCH  64
#define NBLK    (NBATCH * NSEG)   // 2048 blocks = 8/CU

// __builtin_amdgcn_exp2f = v_exp_f32 (2^x); __builtin_amdgcn_logf = v_log_f32 (log2 x)
__device__ __forceinline__ float lse2(float a, float b) {
    float m = fmaxf(a, b);
    float d = fminf(a, b) - m;          // <= 0; -1e30 inputs give exp2 -> 0, no NaN
    return m + __builtin_amdgcn_logf(1.0f + __builtin_amdgcn_exp2f(d));
}

// C = A (x) B in log-semiring; A = later chunk, B = earlier. (x,y,z,w)=(00,01,10,11)
__device__ __forceinline__ float4 mcomb(float4 A, float4 B) {
    return make_float4(lse2(A.x + B.x, A.y + B.z),
                       lse2(A.x + B.y, A.y + B.w),
                       lse2(A.z + B.x, A.w + B.z),
                       lse2(A.z + B.y, A.w + B.w));
}

__global__ __launch_bounds__(NT, 1) void crf_fused_kernel(
    const float* __restrict__ logits,   // (B, 2, T) flat
    const float* __restrict__ trans,    // (2,2)
    float* __restrict__ out,            // out[0]=loss, out[1..]=decoded
    float4* __restrict__ wsM,           // 2048 chunk matrices
    unsigned int* __restrict__ counter) // zeroed by memset node each launch
{
    __shared__ float4 red[NT / 64];     // one slot per wave
    __shared__ int s_last;

    const int blk = blockIdx.x;         // 0..2047
    const int b   = blk >> 5;           // batch
    const int seg = blk & (NSEG - 1);   // segment within batch
    const int tid = threadIdx.x;
    const float K = 1.4426950408889634f;    // log2(e)

    // Each thread owns 8 consecutive timesteps: 2x float4 per channel,
    // all four loads independent and issued up-front (max loads in flight).
    const float* l0 = logits + (size_t)b * (2 * T_LEN) + seg * SEG + tid * STEPS;
    const float* l1 = l0 + T_LEN;
    float* dec = out + 1 + (size_t)b * T_LEN + seg * SEG + tid * STEPS;

    const float4 a0 = ((const float4*)l0)[0];
    const float4 a1 = ((const float4*)l0)[1];
    const float4 c0 = ((const float4*)l1)[0];
    const float4 c1 = ((const float4*)l1)[1];

    const float t00 = trans[0] * K, t01 = trans[1] * K;
    const float t10 = trans[2] * K, t11 = trans[3] * K;

    ((float4*)dec)[0] = make_float4(a0.x >= c0.x ? 0.0f : 1.0f,
                                    a0.y >= c0.y ? 0.0f : 1.0f,
                                    a0.z >= c0.z ? 0.0f : 1.0f,
                                    a0.w >= c0.w ? 0.0f : 1.0f);
    ((float4*)dec)[1] = make_float4(a1.x >= c1.x ? 0.0f : 1.0f,
                                    a1.y >= c1.y ? 0.0f : 1.0f,
                                    a1.z >= c1.z ? 0.0f : 1.0f,
                                    a1.w >= c1.w ? 0.0f : 1.0f);

    // ---- per-thread sequential scan over 8 steps (2x2 transfer matrix) ----
    float m00, m01, m10, m11;
    {
        const float e0 = a0.x * K, e1 = c0.x * K;
        if (blk == 0 && tid == 0) {     // global t=0: alpha0 = emit_0 as diagonal
            m00 = e0; m11 = e1; m01 = -1e30f; m10 = -1e30f;
        } else {
            m00 = t00 + e0; m01 = t01 + e0;
            m10 = t10 + e1; m11 = t11 + e1;
        }
    }
    auto step = [&](float x0, float x1) {
        const float e0 = x0 * K, e1 = x1 * K;
        const float n00 = e0 + lse2(t00 + m00, t01 + m10);
        const float n01 = e0 + lse2(t00 + m01, t01 + m11);
        const float n10 = e1 + lse2(t10 + m00, t11 + m10);
        const float n11 = e1 + lse2(t10 + m01, t11 + m11);
        m00 = n00; m01 = n01; m10 = n10; m11 = n11;
    };
    step(a0.y, c0.y); step(a0.z, c0.z); step(a0.w, c0.w);
    step(a1.x, c1.x); step(a1.y, c1.y); step(a1.z, c1.z); step(a1.w, c1.w);

    // ---- in-wave reduction: 6 shuffle rounds, no barriers ----
    float4 M = make_float4(m00, m01, m10, m11);
    #pragma unroll
    for (int off = 1; off < 64; off <<= 1) {
        float4 Mh;
        Mh.x = __shfl_down(M.x, off);
        Mh.y = __shfl_down(M.y, off);
        Mh.z = __shfl_down(M.z, off);
        Mh.w = __shfl_down(M.w, off);
        const float4 comb = mcomb(Mh, M);   // later (x) earlier
        if ((tid & (2 * off - 1)) == 0) M = comb;
    }
    if ((tid & 63) == 0) red[tid >> 6] = M;
    __syncthreads();

    // ---- publish + last-block final combine (atomic ticket) ----
    if (tid == 0) {
        float4 Acc = red[0];
        #pragma unroll
        for (int w = 1; w < NT / 64; ++w) Acc = mcomb(red[w], Acc);
        wsM[blk] = Acc;
        __threadfence();                         // release
        unsigned int old = atomicAdd(counter, 1u);
        s_last = (old == NBLK - 1) ? 1 : 0;
    }
    __syncthreads();
    if (!s_last) return;
    __threadfence();                             // acquire

    if (tid < NBATCH) {                          // exactly one wave
        float4 Acc = wsM[tid * NSEG];
        #pragma unroll
        for (int s = 1; s < NSEG; ++s) Acc = mcomb(wsM[tid * NSEG + s], Acc);
        // alpha_final[i] = LSE_k M[i][k]; LL2_b = LSE_i alpha_final[i]
        float ll2 = lse2(lse2(Acc.x, Acc.y), lse2(Acc.z, Acc.w));
        #pragma unroll
        for (int off = 32; off >= 1; off >>= 1) ll2 += __shfl_xor(ll2, off);
        if (tid == 0) out[0] = -(0.6931471805599453f * ll2) * (1.0f / (float)NBATCH);
    }
}

extern "C" void kernel_launch(void* const* d_in, const int* in_sizes, int n_in,
                              void* d_out, int out_size, void* d_ws, size_t ws_size,
                              hipStream_t stream) {
    const float* logits = (const float*)d_in[0];
    // d_in[1] = mask: all-ones and unused by the reference computation
    const float* trans  = (const float*)d_in[2];
    float* out  = (float*)d_out;
    float4* wsM = (float4*)d_ws;                          // 2048 * 16 B
    unsigned int* counter = (unsigned int*)((char*)d_ws + NBLK * sizeof(float4));

    hipMemsetAsync(counter, 0, sizeof(unsigned int), stream);
    crf_fused_kernel<<<NBLK, NT, 0, stream>>>(logits, trans, out, wsM, counter);
}